// Round 11
// baseline (200.913 us; speedup 1.0000x reference)
//
#include <hip/hip_runtime.h>
#include <hip/hip_bf16.h>

#define BB 8
#define CC 128
#define HH 128
#define WW 128
#define HW (HH*WW)
#define MD 3
#define ND 49
#define WARP_WEIGHT 2.5f
#define NEG 0.1f

typedef __attribute__((ext_vector_type(8))) short bf16x8;
typedef __attribute__((ext_vector_type(4))) float f32x4;

__device__ inline ushort f2bf(float f) {
    __hip_bfloat16 h = __float2bfloat16(f);
    return *reinterpret_cast<ushort*>(&h);
}
__device__ inline float bf2f(short s) {
    return __uint_as_float(((uint)(ushort)s) << 16);
}

// g8 layout: F[b][y][g][x][8] ushort, g = c/8
#define G8_IDX(b, y, g) ((((size_t)((b) * HH + (y)) * 16) + (g)) * (WW * 8))

// ---------------- flow upsample (bilinear x2, align_corners=False) ----------------
__global__ void k_flow_up(const float* __restrict__ flow, float* __restrict__ flow_up) {
    const int x = threadIdx.x;
    const int y = blockIdx.x;
    const int c = blockIdx.y;
    const int b = blockIdx.z;
    const int Hs = 64, Ws = 64;
    float sy = (y + 0.5f) * 0.5f - 0.5f;
    float sx = (x + 0.5f) * 0.5f - 0.5f;
    float y0f = floorf(sy), x0f = floorf(sx);
    int y0 = (int)y0f, x0 = (int)x0f;
    float wy = sy - y0f, wx = sx - x0f;
    int y0c = min(max(y0, 0), Hs - 1), y1c = min(max(y0 + 1, 0), Hs - 1);
    int x0c = min(max(x0, 0), Ws - 1), x1c = min(max(x0 + 1, 0), Ws - 1);
    const float* src = flow + ((size_t)(b * 2 + c)) * Hs * Ws;
    float v00 = src[y0c * Ws + x0c], v01 = src[y0c * Ws + x1c];
    float v10 = src[y1c * Ws + x0c], v11 = src[y1c * Ws + x1c];
    float v = v00 * (1.f - wx) * (1.f - wy) + v01 * wx * (1.f - wy)
            + v10 * (1.f - wx) * wy + v11 * wx * wy;
    flow_up[((size_t)(b * 2 + c) * HH + y) * WW + x] = v;
}

// ---------------- f2 planar f32 -> channel-last bf16 [b][y][x][128] via LDS ----------------
__global__ __launch_bounds__(256) void k_prep_cl(const float* __restrict__ src,
                                                 ushort* __restrict__ dstcl) {
    __shared__ ushort lds[128][68];
    const int y = blockIdx.x & 127;
    const int b = (blockIdx.x >> 7) & 7;
    const int chunk = blockIdx.x >> 10;      // 0..1 (64 channels each)
    {
        const int x = threadIdx.x & 127;
        const int cg = threadIdx.x >> 7;     // 0..1 -> 32 ch each
        const int c0 = chunk * 64 + cg * 32;
        const float* s = src + ((size_t)b * CC + c0) * HW + y * WW + x;
#pragma unroll
        for (int j4 = 0; j4 < 8; j4++) {
            ushort t[4];
#pragma unroll
            for (int u = 0; u < 4; u++) t[u] = f2bf(s[(size_t)(j4 * 4 + u) * HW]);
            *reinterpret_cast<uint2*>(&lds[x][cg * 32 + j4 * 4]) =
                *reinterpret_cast<const uint2*>(t);
        }
    }
    __syncthreads();
    {
        const int xw = threadIdx.x >> 1;
        const int h = threadIdx.x & 1;
        ushort* d = dstcl + (((size_t)(b * HH + y)) * WW + xw) * CC + chunk * 64 + h * 32;
#pragma unroll
        for (int i = 0; i < 8; i++)
            *reinterpret_cast<uint2*>(d + i * 4) =
                *reinterpret_cast<const uint2*>(&lds[xw][h * 32 + i * 4]);
    }
}

// ---------------- backward warp: CL gather -> g8 store ----------------
__global__ __launch_bounds__(256) void k_warp2(const ushort* __restrict__ f2cl,
                                               const float* __restrict__ flow_up,
                                               ushort* __restrict__ f2wg8) {
    const int bid = blockIdx.x;          // 8192
    const int k = bid & 7;               // XCD band
    const int t = bid >> 3;              // 0..1023
    const int xs = t & 7;
    const int y  = k * 16 + ((t >> 3) & 15);
    const int b  = t >> 7;
    const int p  = threadIdx.x >> 4;     // pixel in block (0..15)
    const int g  = threadIdx.x & 15;     // channel group (8 ch)
    const int x  = xs * 16 + p;

    const float fx = flow_up[((size_t)(b * 2 + 0) * HH + y) * WW + x] * WARP_WEIGHT;
    const float fy = flow_up[((size_t)(b * 2 + 1) * HH + y) * WW + x] * WARP_WEIGHT;
    const float sx = (float)x + fx;
    const float sy = (float)y + fy;
    float x0f = floorf(sx), y0f = floorf(sy);
    int x0 = (int)x0f, y0 = (int)y0f;
    float wx = sx - x0f, wy = sy - y0f;
    int x0c = min(max(x0, 0), WW - 1), x1c = min(max(x0 + 1, 0), WW - 1);
    int y0c = min(max(y0, 0), HH - 1), y1c = min(max(y0 + 1, 0), HH - 1);
    bool vx0 = (x0 >= 0) & (x0 < WW);
    bool vx1 = (x0 + 1 >= 0) & (x0 + 1 < WW);
    bool vy0 = (y0 >= 0) & (y0 < HH);
    bool vy1 = (y0 + 1 >= 0) & (y0 + 1 < HH);
    float w00 = (vx0 && vy0) ? (1.f - wx) * (1.f - wy) : 0.f;
    float w01 = (vx1 && vy0) ? wx * (1.f - wy) : 0.f;
    float w10 = (vx0 && vy1) ? (1.f - wx) * wy : 0.f;
    float w11 = (vx1 && vy1) ? wx * wy : 0.f;

    const ushort* base = f2cl + (size_t)b * HW * CC + (size_t)g * 8;
    bf16x8 t00 = *reinterpret_cast<const bf16x8*>(base + ((size_t)y0c * WW + x0c) * CC);
    bf16x8 t01 = *reinterpret_cast<const bf16x8*>(base + ((size_t)y0c * WW + x1c) * CC);
    bf16x8 t10 = *reinterpret_cast<const bf16x8*>(base + ((size_t)y1c * WW + x0c) * CC);
    bf16x8 t11 = *reinterpret_cast<const bf16x8*>(base + ((size_t)y1c * WW + x1c) * CC);

    ushort o[8];
#pragma unroll
    for (int j = 0; j < 8; j++) {
        float v = w00 * bf2f(t00[j]) + w01 * bf2f(t01[j])
                + w10 * bf2f(t10[j]) + w11 * bf2f(t11[j]);
        o[j] = f2bf(v);
    }
    *reinterpret_cast<uint4*>(f2wg8 + G8_IDX(b, y, g) + x * 8) =
        *reinterpret_cast<const uint4*>(o);
}

// ---------------- f1 planar f32 -> g8 bf16 ----------------
__global__ __launch_bounds__(256) void k_prep_f1(const float* __restrict__ f1,
                                                 ushort* __restrict__ f1g8) {
    const int bid = blockIdx.x;            // 4096
    const int y = bid & 127;
    const int b = (bid >> 7) & 7;
    const int chunk = bid >> 10;           // 0..3
    const int x  = threadIdx.x & 127;
    const int cg = threadIdx.x >> 7;
    const int c0 = chunk * 32 + cg * 16;
    const float* src = f1 + ((size_t)b * CC + c0) * HW + y * WW + x;
#pragma unroll
    for (int gi = 0; gi < 2; gi++) {
        ushort tmp[8];
#pragma unroll
        for (int j = 0; j < 8; j++) tmp[j] = f2bf(src[(size_t)(gi * 8 + j) * HW]);
        *reinterpret_cast<uint4*>(f1g8 + G8_IDX(b, y, (c0 >> 3) + gi) + x * 8) =
            *reinterpret_cast<const uint4*>(tmp);
    }
}

// ---------------- MFMA cost volume v4: XCD-banded grid + LDS-staged output + B prefetch ----
__global__ __launch_bounds__(512) void k_corr_mfma(const ushort* __restrict__ f1g8,
                                                   const ushort* __restrict__ f2g8,
                                                   ushort* __restrict__ Ct) {
    __shared__ ushort cstage[128][68];     // 17.4 KB
    const int b  = blockIdx.x & 7;
    const int y  = blockIdx.x >> 3;
    const int w  = threadIdx.x >> 6;       // x-tile 0..7
    const int l  = threadIdx.x & 63;
    const int lx = l & 15;
    const int lk = l >> 4;
    const int xa0 = w * 16;

    {
        const int px = threadIdx.x >> 2;
        const int part = threadIdx.x & 3;
        uint2 z = {0u, 0u};
        *reinterpret_cast<uint2*>(&cstage[px][48 + part * 4]) = z;
    }
    __syncthreads();

    bf16x8 afr[4];
#pragma unroll
    for (int kk = 0; kk < 4; kk++)
        afr[kk] = *reinterpret_cast<const bf16x8*>(
            f1g8 + G8_IDX(b, y, kk * 4 + lk) + (xa0 + lx) * 8);

    const int xb0 = xa0 - 3 + lx;
    const int xb1 = xa0 + 13 + lx;
    const float scale = 1.f / (float)CC;

    bf16x8 bb[2][8];
    auto load_b = [&](int dy, int buf) {
        const int yy = y + dy - MD;
        const bool yv = (unsigned)yy < (unsigned)HH;
#pragma unroll
        for (int kk = 0; kk < 4; kk++) {
            const ushort* grp = f2g8 + G8_IDX(b, yy, kk * 4 + lk);
            bf16x8 b0 = {}, b1 = {};
            if (yv && (unsigned)xb0 < (unsigned)WW)
                b0 = *reinterpret_cast<const bf16x8*>(grp + xb0 * 8);
            if (yv && (unsigned)xb1 < (unsigned)WW)
                b1 = *reinterpret_cast<const bf16x8*>(grp + xb1 * 8);
            bb[buf][kk * 2 + 0] = b0;
            bb[buf][kk * 2 + 1] = b1;
        }
    };

    load_b(0, 0);
#pragma unroll
    for (int dy = 0; dy < 7; dy++) {
        if (dy + 1 < 7) load_b(dy + 1, (dy + 1) & 1);
        f32x4 acc0 = (f32x4)(0.f), acc1 = (f32x4)(0.f);
#pragma unroll
        for (int kk = 0; kk < 4; kk++) {
            acc0 = __builtin_amdgcn_mfma_f32_16x16x32_bf16(
                afr[kk], bb[dy & 1][kk * 2 + 0], acc0, 0, 0, 0);
            acc1 = __builtin_amdgcn_mfma_f32_16x16x32_bf16(
                afr[kk], bb[dy & 1][kk * 2 + 1], acc1, 0, 0, 0);
        }
#pragma unroll
        for (int r = 0; r < 4; r++) {
            const int i = lk * 4 + r;
            const int d0 = lx - i;
            if (d0 >= 0 && d0 <= 6)
                cstage[xa0 + i][dy * 7 + d0] = f2bf(acc0[r] * scale);
            const int d1 = lx - i + 16;
            if (d1 >= 0 && d1 <= 6)
                cstage[xa0 + i][dy * 7 + d1] = f2bf(acc1[r] * scale);
        }
    }
    __syncthreads();

    {
        const int px = threadIdx.x >> 2;
        const int part = threadIdx.x & 3;
        ushort* dst = Ct + (((size_t)(b * HH + y)) * WW + px) * 64 + part * 16;
        uint2 t0 = *reinterpret_cast<const uint2*>(&cstage[px][part * 16 + 0]);
        uint2 t1 = *reinterpret_cast<const uint2*>(&cstage[px][part * 16 + 4]);
        uint2 t2 = *reinterpret_cast<const uint2*>(&cstage[px][part * 16 + 8]);
        uint2 t3 = *reinterpret_cast<const uint2*>(&cstage[px][part * 16 + 12]);
        uint4 v0; v0.x = t0.x; v0.y = t0.y; v0.z = t1.x; v0.w = t1.y;
        uint4 v1; v1.x = t2.x; v1.y = t2.y; v1.z = t3.x; v1.w = t3.y;
        *reinterpret_cast<uint4*>(dst) = v0;
        *reinterpret_cast<uint4*>(dst + 8) = v1;
    }
}

// ---------------- weight transpose + bf16: w[OC][IC][K][K] -> Wt[K*K][OCPW][ICP] ----------------
template<int IC, int ICP, int OC, int OCP, int KK>
__global__ void k_prep_w(const float* __restrict__ w, ushort* __restrict__ Wt) {
    int e = blockIdx.x * 256 + threadIdx.x;
    const int total = KK * KK * OCP * ICP;
    if (e >= total) return;
    int ic = e % ICP;
    int oc = (e / ICP) % OCP;
    int tap = e / (ICP * OCP);
    int kh = tap / KK, kw = tap % KK;
    float v = 0.f;
    if (oc < OC && ic < IC) v = w[((oc * IC + ic) * KK + kh) * KK + kw];
    Wt[e] = f2bf(v);
}

// ---------------- implicit-GEMM MFMA conv v2 ----------------
// MT oc-tiles/wave (grid.z splits OC), NT px-tiles/wave; 4 waves/block.
// abuf double-buffered (1 tap ahead), bbuf triple-buffered (2 taps ahead).
template<int ICP, int OCPW, int MT, int NT, int OCOUT, int KK, int PAD, bool RELU, bool LAST>
__global__ __launch_bounds__(256, 4) void k_conv_mfma(
    const ushort* __restrict__ In, const ushort* __restrict__ Wt,
    const float* __restrict__ bias, ushort* __restrict__ Out,
    const float* __restrict__ flow_up, float* __restrict__ fout)
{
    constexpr int NCH = ICP / 32;
    constexpr int NTAP = KK * KK * NCH;
    constexpr int WPR = 8 / NT;           // waves per row
    constexpr int RPB = 4 / WPR;          // rows per block
    const int w = threadIdx.x >> 6;
    const int l = threadIdx.x & 63;
    const int lx = l & 15;
    const int lk = l >> 4;
    const int y = blockIdx.x * RPB + w / WPR;
    const int n0 = (w % WPR) * (16 * NT);
    const int b = blockIdx.y;
    const int ocb = blockIdx.z * (MT * 16);

    const ushort* inbase = In + (size_t)b * HH * WW * ICP;

    f32x4 acc[MT][NT];
#pragma unroll
    for (int m = 0; m < MT; m++)
#pragma unroll
        for (int nt = 0; nt < NT; nt++) acc[m][nt] = (f32x4)(0.f);

    bf16x8 abuf[2][MT];
    bf16x8 bbuf[3][NT];

    auto load_a = [&](int t, int buf) {
        const int kh = t / (KK * NCH);
        const int kw = (t / NCH) % KK;
        const int ch = t % NCH;
        const int k0 = ch * 32 + lk * 8;
        const ushort* wtap = Wt + (size_t)(kh * KK + kw) * OCPW * ICP;
#pragma unroll
        for (int m = 0; m < MT; m++)
            abuf[buf][m] = *reinterpret_cast<const bf16x8*>(
                wtap + (ocb + m * 16 + lx) * ICP + k0);
    };
    auto load_b = [&](int t, int buf) {
        const int kh = t / (KK * NCH);
        const int kw = (t / NCH) % KK;
        const int ch = t % NCH;
        const int k0 = ch * 32 + lk * 8;
        const int yy = y + kh - PAD;
        const bool yv = (unsigned)yy < (unsigned)HH;
        const ushort* inrow = inbase + (size_t)yy * WW * ICP;
#pragma unroll
        for (int nt = 0; nt < NT; nt++) {
            int xx = n0 + nt * 16 + lx + kw - PAD;
            bf16x8 v = {};
            if (yv && (unsigned)xx < (unsigned)WW)
                v = *reinterpret_cast<const bf16x8*>(inrow + (size_t)xx * ICP + k0);
            bbuf[buf][nt] = v;
        }
    };

    load_b(0, 0);
    if (NTAP > 1) load_b(1, 1);
    load_a(0, 0);
#pragma unroll
    for (int t = 0; t < NTAP; t++) {
        if (t + 2 < NTAP) load_b(t + 2, (t + 2) % 3);
        if (t + 1 < NTAP) load_a(t + 1, (t + 1) & 1);
#pragma unroll
        for (int nt = 0; nt < NT; nt++)
#pragma unroll
            for (int m = 0; m < MT; m++)
                acc[m][nt] = __builtin_amdgcn_mfma_f32_16x16x32_bf16(
                    abuf[t & 1][m], bbuf[t % 3][nt], acc[m][nt], 0, 0, 0);
    }

    if (!LAST) {
#pragma unroll
        for (int m = 0; m < MT; m++) {
            const int oc0 = ocb + m * 16 + lk * 4;
            float4 bs = *reinterpret_cast<const float4*>(bias + oc0);
#pragma unroll
            for (int nt = 0; nt < NT; nt++) {
                int x = n0 + nt * 16 + lx;
                float v0 = acc[m][nt][0] + bs.x;
                float v1 = acc[m][nt][1] + bs.y;
                float v2 = acc[m][nt][2] + bs.z;
                float v3 = acc[m][nt][3] + bs.w;
                if (RELU) {
                    v0 = (v0 >= 0.f) ? v0 : NEG * v0;
                    v1 = (v1 >= 0.f) ? v1 : NEG * v1;
                    v2 = (v2 >= 0.f) ? v2 : NEG * v2;
                    v3 = (v3 >= 0.f) ? v3 : NEG * v3;
                }
                ushort4 o;
                o.x = f2bf(v0); o.y = f2bf(v1); o.z = f2bf(v2); o.w = f2bf(v3);
                *reinterpret_cast<ushort4*>(Out + (((size_t)(b * HH + y)) * WW + x) * OCOUT + oc0) = o;
            }
        }
    } else {
        if (lk == 0) {
#pragma unroll
            for (int nt = 0; nt < NT; nt++) {
                int x = n0 + nt * 16 + lx;
#pragma unroll
                for (int r = 0; r < 2; r++) {
                    size_t o = (((size_t)(b * 2 + r)) * HH + y) * WW + x;
                    fout[o] = acc[0][nt][r] + bias[r] + flow_up[o];
                }
            }
        }
    }
}

extern "C" void kernel_launch(void* const* d_in, const int* in_sizes, int n_in,
                              void* d_out, int out_size, void* d_ws, size_t ws_size,
                              hipStream_t stream) {
    const float* f1   = (const float*)d_in[0];
    const float* f2   = (const float*)d_in[1];
    const float* flow = (const float*)d_in[2];
    const float* w1   = (const float*)d_in[3];
    const float* b1   = (const float*)d_in[4];
    const float* w2   = (const float*)d_in[5];
    const float* b2   = (const float*)d_in[6];
    const float* w3   = (const float*)d_in[7];
    const float* b3   = (const float*)d_in[8];
    float* out = (float*)d_out;

    char* ws = (char*)d_ws;
    const size_t SZ_FLOWUP = (size_t)BB * 2 * HW * 4;          // 1.0 MB
    const size_t SZ_CT     = (size_t)BB * HW * 64 * 2;         // 16.8 MB
    const size_t SZ_WT1    = (size_t)9 * 64 * 64 * 2;
    const size_t SZ_WT2    = (size_t)9 * 32 * 64 * 2;
    const size_t SZ_WT3    = (size_t)25 * 16 * 32 * 2;
    const size_t SZ_BUF    = (size_t)BB * HW * CC * 2;         // 33.5 MB

    float*  flow_up = (float*)ws;                         ws += SZ_FLOWUP;
    ushort* Ct      = (ushort*)ws;                        ws += SZ_CT;
    ushort* Wt1     = (ushort*)ws;                        ws += SZ_WT1;
    ushort* Wt2     = (ushort*)ws;                        ws += SZ_WT2;
    ushort* Wt3     = (ushort*)ws;                        ws += SZ_WT3;
    ushort* f2wg8   = (ushort*)ws;                        ws += SZ_BUF;   // bufB
    ushort* bufA    = (ushort*)ws;                        // f2cl -> f1g8 -> h1/h2
    ushort* f2cl    = bufA;
    ushort* f1g8    = bufA;
    ushort* h1      = bufA;
    ushort* h2      = (ushort*)((char*)bufA + (size_t)BB * HW * 64 * 2);

    k_prep_w<49, 64, 64, 64, 3><<<dim3((9 * 64 * 64 + 255) / 256), dim3(256), 0, stream>>>(w1, Wt1);
    k_prep_w<64, 64, 32, 32, 3><<<dim3((9 * 32 * 64 + 255) / 256), dim3(256), 0, stream>>>(w2, Wt2);
    k_prep_w<32, 32, 2, 16, 5><<<dim3((25 * 16 * 32 + 255) / 256), dim3(256), 0, stream>>>(w3, Wt3);

    k_flow_up<<<dim3(HH, 2, BB), dim3(WW), 0, stream>>>(flow, flow_up);
    k_prep_cl<<<dim3(2048), dim3(256), 0, stream>>>(f2, f2cl);
    k_warp2  <<<dim3(8192), dim3(256), 0, stream>>>(f2cl, flow_up, f2wg8);
    k_prep_f1<<<dim3(4096), dim3(256), 0, stream>>>(f1, f1g8);   // overwrites bufA (f2cl dead)
    k_corr_mfma<<<dim3(1024), dim3(512), 0, stream>>>(f1g8, f2wg8, Ct);

    // conv1: MT=2 (OC split via grid.z=2), NT=4 -> 1024 blocks, 4096 waves
    k_conv_mfma<64, 64, 2, 4, 64, 3, 1, true,  false>
        <<<dim3(HH / 2, BB, 2), dim3(256), 0, stream>>>(Ct, Wt1, b1, h1, nullptr, nullptr);
    // conv2: MT=2 (full 32 oc), NT=2 -> 1024 blocks, 4096 waves
    k_conv_mfma<64, 32, 2, 2, 32, 3, 1, true,  false>
        <<<dim3(HH, BB, 1), dim3(256), 0, stream>>>(h1, Wt2, b2, h2, nullptr, nullptr);
    // conv3: MT=1, NT=2 -> 1024 blocks, 4096 waves
    k_conv_mfma<32, 16, 1, 2, 2,  5, 2, false, true >
        <<<dim3(HH, BB, 1), dim3(256), 0, stream>>>(h2, Wt3, b3, nullptr, flow_up, out);
}

// Round 12
// 193.642 us; speedup vs baseline: 1.0375x; 1.0375x over previous
//
#include <hip/hip_runtime.h>
#include <hip/hip_bf16.h>

#define BB 8
#define CC 128
#define HH 128
#define WW 128
#define HW (HH*WW)
#define MD 3
#define ND 49
#define WARP_WEIGHT 2.5f
#define NEG 0.1f

typedef __attribute__((ext_vector_type(8))) short bf16x8;
typedef __attribute__((ext_vector_type(4))) float f32x4;

__device__ inline ushort f2bf(float f) {
    __hip_bfloat16 h = __float2bfloat16(f);
    return *reinterpret_cast<ushort*>(&h);
}
__device__ inline float bf2f(short s) {
    return __uint_as_float(((uint)(ushort)s) << 16);
}

// g8 layout: F[b][y][g][x][8] ushort, g = c/8
#define G8_IDX(b, y, g) ((((size_t)((b) * HH + (y)) * 16) + (g)) * (WW * 8))

// ---------------- flow upsample (bilinear x2, align_corners=False) ----------------
__global__ void k_flow_up(const float* __restrict__ flow, float* __restrict__ flow_up) {
    const int x = threadIdx.x;
    const int y = blockIdx.x;
    const int c = blockIdx.y;
    const int b = blockIdx.z;
    const int Hs = 64, Ws = 64;
    float sy = (y + 0.5f) * 0.5f - 0.5f;
    float sx = (x + 0.5f) * 0.5f - 0.5f;
    float y0f = floorf(sy), x0f = floorf(sx);
    int y0 = (int)y0f, x0 = (int)x0f;
    float wy = sy - y0f, wx = sx - x0f;
    int y0c = min(max(y0, 0), Hs - 1), y1c = min(max(y0 + 1, 0), Hs - 1);
    int x0c = min(max(x0, 0), Ws - 1), x1c = min(max(x0 + 1, 0), Ws - 1);
    const float* src = flow + ((size_t)(b * 2 + c)) * Hs * Ws;
    float v00 = src[y0c * Ws + x0c], v01 = src[y0c * Ws + x1c];
    float v10 = src[y1c * Ws + x0c], v11 = src[y1c * Ws + x1c];
    float v = v00 * (1.f - wx) * (1.f - wy) + v01 * wx * (1.f - wy)
            + v10 * (1.f - wx) * wy + v11 * wx * wy;
    flow_up[((size_t)(b * 2 + c) * HH + y) * WW + x] = v;
}

// ---------------- f2 planar f32 -> channel-last bf16 [b][y][x][128] via LDS ----------------
__global__ __launch_bounds__(256) void k_prep_cl(const float* __restrict__ src,
                                                 ushort* __restrict__ dstcl) {
    __shared__ ushort lds[128][68];
    const int y = blockIdx.x & 127;
    const int b = (blockIdx.x >> 7) & 7;
    const int chunk = blockIdx.x >> 10;      // 0..1 (64 channels each)
    {
        const int x = threadIdx.x & 127;
        const int cg = threadIdx.x >> 7;     // 0..1 -> 32 ch each
        const int c0 = chunk * 64 + cg * 32;
        const float* s = src + ((size_t)b * CC + c0) * HW + y * WW + x;
#pragma unroll
        for (int j4 = 0; j4 < 8; j4++) {
            ushort t[4];
#pragma unroll
            for (int u = 0; u < 4; u++) t[u] = f2bf(s[(size_t)(j4 * 4 + u) * HW]);
            *reinterpret_cast<uint2*>(&lds[x][cg * 32 + j4 * 4]) =
                *reinterpret_cast<const uint2*>(t);
        }
    }
    __syncthreads();
    {
        const int xw = threadIdx.x >> 1;
        const int h = threadIdx.x & 1;
        ushort* d = dstcl + (((size_t)(b * HH + y)) * WW + xw) * CC + chunk * 64 + h * 32;
#pragma unroll
        for (int i = 0; i < 8; i++)
            *reinterpret_cast<uint2*>(d + i * 4) =
                *reinterpret_cast<const uint2*>(&lds[xw][h * 32 + i * 4]);
    }
}

// ---------------- backward warp: CL gather -> g8 store ----------------
__global__ __launch_bounds__(256) void k_warp2(const ushort* __restrict__ f2cl,
                                               const float* __restrict__ flow_up,
                                               ushort* __restrict__ f2wg8) {
    const int bid = blockIdx.x;          // 8192
    const int k = bid & 7;               // XCD band
    const int t = bid >> 3;              // 0..1023
    const int xs = t & 7;
    const int y  = k * 16 + ((t >> 3) & 15);
    const int b  = t >> 7;
    const int p  = threadIdx.x >> 4;     // pixel in block (0..15)
    const int g  = threadIdx.x & 15;     // channel group (8 ch)
    const int x  = xs * 16 + p;

    const float fx = flow_up[((size_t)(b * 2 + 0) * HH + y) * WW + x] * WARP_WEIGHT;
    const float fy = flow_up[((size_t)(b * 2 + 1) * HH + y) * WW + x] * WARP_WEIGHT;
    const float sx = (float)x + fx;
    const float sy = (float)y + fy;
    float x0f = floorf(sx), y0f = floorf(sy);
    int x0 = (int)x0f, y0 = (int)y0f;
    float wx = sx - x0f, wy = sy - y0f;
    int x0c = min(max(x0, 0), WW - 1), x1c = min(max(x0 + 1, 0), WW - 1);
    int y0c = min(max(y0, 0), HH - 1), y1c = min(max(y0 + 1, 0), HH - 1);
    bool vx0 = (x0 >= 0) & (x0 < WW);
    bool vx1 = (x0 + 1 >= 0) & (x0 + 1 < WW);
    bool vy0 = (y0 >= 0) & (y0 < HH);
    bool vy1 = (y0 + 1 >= 0) & (y0 + 1 < HH);
    float w00 = (vx0 && vy0) ? (1.f - wx) * (1.f - wy) : 0.f;
    float w01 = (vx1 && vy0) ? wx * (1.f - wy) : 0.f;
    float w10 = (vx0 && vy1) ? (1.f - wx) * wy : 0.f;
    float w11 = (vx1 && vy1) ? wx * wy : 0.f;

    const ushort* base = f2cl + (size_t)b * HW * CC + (size_t)g * 8;
    bf16x8 t00 = *reinterpret_cast<const bf16x8*>(base + ((size_t)y0c * WW + x0c) * CC);
    bf16x8 t01 = *reinterpret_cast<const bf16x8*>(base + ((size_t)y0c * WW + x1c) * CC);
    bf16x8 t10 = *reinterpret_cast<const bf16x8*>(base + ((size_t)y1c * WW + x0c) * CC);
    bf16x8 t11 = *reinterpret_cast<const bf16x8*>(base + ((size_t)y1c * WW + x1c) * CC);

    ushort o[8];
#pragma unroll
    for (int j = 0; j < 8; j++) {
        float v = w00 * bf2f(t00[j]) + w01 * bf2f(t01[j])
                + w10 * bf2f(t10[j]) + w11 * bf2f(t11[j]);
        o[j] = f2bf(v);
    }
    *reinterpret_cast<uint4*>(f2wg8 + G8_IDX(b, y, g) + x * 8) =
        *reinterpret_cast<const uint4*>(o);
}

// ---------------- f1 planar f32 -> g8 bf16 ----------------
__global__ __launch_bounds__(256) void k_prep_f1(const float* __restrict__ f1,
                                                 ushort* __restrict__ f1g8) {
    const int bid = blockIdx.x;            // 4096
    const int y = bid & 127;
    const int b = (bid >> 7) & 7;
    const int chunk = bid >> 10;           // 0..3
    const int x  = threadIdx.x & 127;
    const int cg = threadIdx.x >> 7;
    const int c0 = chunk * 32 + cg * 16;
    const float* src = f1 + ((size_t)b * CC + c0) * HW + y * WW + x;
#pragma unroll
    for (int gi = 0; gi < 2; gi++) {
        ushort tmp[8];
#pragma unroll
        for (int j = 0; j < 8; j++) tmp[j] = f2bf(src[(size_t)(gi * 8 + j) * HW]);
        *reinterpret_cast<uint4*>(f1g8 + G8_IDX(b, y, (c0 >> 3) + gi) + x * 8) =
            *reinterpret_cast<const uint4*>(tmp);
    }
}

// ---------------- MFMA cost volume v4: XCD-banded grid + LDS-staged output + B prefetch ----
__global__ __launch_bounds__(512) void k_corr_mfma(const ushort* __restrict__ f1g8,
                                                   const ushort* __restrict__ f2g8,
                                                   ushort* __restrict__ Ct) {
    __shared__ ushort cstage[128][68];     // 17.4 KB
    const int b  = blockIdx.x & 7;
    const int y  = blockIdx.x >> 3;
    const int w  = threadIdx.x >> 6;       // x-tile 0..7
    const int l  = threadIdx.x & 63;
    const int lx = l & 15;
    const int lk = l >> 4;
    const int xa0 = w * 16;

    {
        const int px = threadIdx.x >> 2;
        const int part = threadIdx.x & 3;
        uint2 z = {0u, 0u};
        *reinterpret_cast<uint2*>(&cstage[px][48 + part * 4]) = z;
    }
    __syncthreads();

    bf16x8 afr[4];
#pragma unroll
    for (int kk = 0; kk < 4; kk++)
        afr[kk] = *reinterpret_cast<const bf16x8*>(
            f1g8 + G8_IDX(b, y, kk * 4 + lk) + (xa0 + lx) * 8);

    const int xb0 = xa0 - 3 + lx;
    const int xb1 = xa0 + 13 + lx;
    const float scale = 1.f / (float)CC;

    bf16x8 bb[2][8];
    auto load_b = [&](int dy, int buf) {
        const int yy = y + dy - MD;
        const bool yv = (unsigned)yy < (unsigned)HH;
#pragma unroll
        for (int kk = 0; kk < 4; kk++) {
            const ushort* grp = f2g8 + G8_IDX(b, yy, kk * 4 + lk);
            bf16x8 b0 = {}, b1 = {};
            if (yv && (unsigned)xb0 < (unsigned)WW)
                b0 = *reinterpret_cast<const bf16x8*>(grp + xb0 * 8);
            if (yv && (unsigned)xb1 < (unsigned)WW)
                b1 = *reinterpret_cast<const bf16x8*>(grp + xb1 * 8);
            bb[buf][kk * 2 + 0] = b0;
            bb[buf][kk * 2 + 1] = b1;
        }
    };

    load_b(0, 0);
#pragma unroll
    for (int dy = 0; dy < 7; dy++) {
        if (dy + 1 < 7) load_b(dy + 1, (dy + 1) & 1);
        f32x4 acc0 = (f32x4)(0.f), acc1 = (f32x4)(0.f);
#pragma unroll
        for (int kk = 0; kk < 4; kk++) {
            acc0 = __builtin_amdgcn_mfma_f32_16x16x32_bf16(
                afr[kk], bb[dy & 1][kk * 2 + 0], acc0, 0, 0, 0);
            acc1 = __builtin_amdgcn_mfma_f32_16x16x32_bf16(
                afr[kk], bb[dy & 1][kk * 2 + 1], acc1, 0, 0, 0);
        }
#pragma unroll
        for (int r = 0; r < 4; r++) {
            const int i = lk * 4 + r;
            const int d0 = lx - i;
            if (d0 >= 0 && d0 <= 6)
                cstage[xa0 + i][dy * 7 + d0] = f2bf(acc0[r] * scale);
            const int d1 = lx - i + 16;
            if (d1 >= 0 && d1 <= 6)
                cstage[xa0 + i][dy * 7 + d1] = f2bf(acc1[r] * scale);
        }
    }
    __syncthreads();

    {
        const int px = threadIdx.x >> 2;
        const int part = threadIdx.x & 3;
        ushort* dst = Ct + (((size_t)(b * HH + y)) * WW + px) * 64 + part * 16;
        uint2 t0 = *reinterpret_cast<const uint2*>(&cstage[px][part * 16 + 0]);
        uint2 t1 = *reinterpret_cast<const uint2*>(&cstage[px][part * 16 + 4]);
        uint2 t2 = *reinterpret_cast<const uint2*>(&cstage[px][part * 16 + 8]);
        uint2 t3 = *reinterpret_cast<const uint2*>(&cstage[px][part * 16 + 12]);
        uint4 v0; v0.x = t0.x; v0.y = t0.y; v0.z = t1.x; v0.w = t1.y;
        uint4 v1; v1.x = t2.x; v1.y = t2.y; v1.z = t3.x; v1.w = t3.y;
        *reinterpret_cast<uint4*>(dst) = v0;
        *reinterpret_cast<uint4*>(dst + 8) = v1;
    }
}

// ---------------- weight transpose + bf16: w[OC][IC][K][K] -> Wt[K*K][OCP][ICP] ----------------
template<int IC, int ICP, int OC, int OCP, int KK>
__global__ void k_prep_w(const float* __restrict__ w, ushort* __restrict__ Wt) {
    int e = blockIdx.x * 256 + threadIdx.x;
    const int total = KK * KK * OCP * ICP;
    if (e >= total) return;
    int ic = e % ICP;
    int oc = (e / ICP) % OCP;
    int tap = e / (ICP * OCP);
    int kh = tap / KK, kw = tap % KK;
    float v = 0.f;
    if (oc < OC && ic < IC) v = w[((oc * IC + ic) * KK + kh) * KK + kw];
    Wt[e] = f2bf(v);
}

// ---------------- implicit-GEMM MFMA conv v3 ----------------
// Full OC per wave (MT tiles -> full-line stores). NT px-tiles/wave; 4 waves = 1 row.
// abuf 1 tap ahead, bbuf 2 taps ahead (triple buffer), all statically indexed.
template<int ICP, int OCP, int MT, int NT, int OCOUT, int KK, int PAD, bool RELU, bool LAST>
__global__ __launch_bounds__(256, 4) void k_conv_mfma(
    const ushort* __restrict__ In, const ushort* __restrict__ Wt,
    const float* __restrict__ bias, ushort* __restrict__ Out,
    const float* __restrict__ flow_up, float* __restrict__ fout)
{
    constexpr int NCH = ICP / 32;
    constexpr int NTAP = KK * KK * NCH;
    const int w = threadIdx.x >> 6;       // 0..3: px quarter of the row
    const int l = threadIdx.x & 63;
    const int lx = l & 15;
    const int lk = l >> 4;
    const int y = blockIdx.x;
    const int n0 = w * (16 * NT);
    const int b = blockIdx.y;

    const ushort* inbase = In + (size_t)b * HH * WW * ICP;

    f32x4 acc[MT][NT];
#pragma unroll
    for (int m = 0; m < MT; m++)
#pragma unroll
        for (int nt = 0; nt < NT; nt++) acc[m][nt] = (f32x4)(0.f);

    bf16x8 abuf[2][MT];
    bf16x8 bbuf[3][NT];

    auto load_a = [&](int t, int buf) {
        const int kh = t / (KK * NCH);
        const int kw = (t / NCH) % KK;
        const int ch = t % NCH;
        const int k0 = ch * 32 + lk * 8;
        const ushort* wtap = Wt + (size_t)(kh * KK + kw) * OCP * ICP;
#pragma unroll
        for (int m = 0; m < MT; m++)
            abuf[buf][m] = *reinterpret_cast<const bf16x8*>(wtap + (m * 16 + lx) * ICP + k0);
    };
    auto load_b = [&](int t, int buf) {
        const int kh = t / (KK * NCH);
        const int kw = (t / NCH) % KK;
        const int ch = t % NCH;
        const int k0 = ch * 32 + lk * 8;
        const int yy = y + kh - PAD;
        const bool yv = (unsigned)yy < (unsigned)HH;
        const ushort* inrow = inbase + (size_t)yy * WW * ICP;
#pragma unroll
        for (int nt = 0; nt < NT; nt++) {
            int xx = n0 + nt * 16 + lx + kw - PAD;
            bf16x8 v = {};
            if (yv && (unsigned)xx < (unsigned)WW)
                v = *reinterpret_cast<const bf16x8*>(inrow + (size_t)xx * ICP + k0);
            bbuf[buf][nt] = v;
        }
    };

    load_b(0, 0);
    if (NTAP > 1) load_b(1, 1);
    load_a(0, 0);
#pragma unroll
    for (int t = 0; t < NTAP; t++) {
        if (t + 2 < NTAP) load_b(t + 2, (t + 2) % 3);
        if (t + 1 < NTAP) load_a(t + 1, (t + 1) & 1);
#pragma unroll
        for (int nt = 0; nt < NT; nt++)
#pragma unroll
            for (int m = 0; m < MT; m++)
                acc[m][nt] = __builtin_amdgcn_mfma_f32_16x16x32_bf16(
                    abuf[t & 1][m], bbuf[t % 3][nt], acc[m][nt], 0, 0, 0);
    }

    if (!LAST) {
#pragma unroll
        for (int m = 0; m < MT; m++) {
            const int oc0 = m * 16 + lk * 4;
            float4 bs = *reinterpret_cast<const float4*>(bias + oc0);
#pragma unroll
            for (int nt = 0; nt < NT; nt++) {
                int x = n0 + nt * 16 + lx;
                float v0 = acc[m][nt][0] + bs.x;
                float v1 = acc[m][nt][1] + bs.y;
                float v2 = acc[m][nt][2] + bs.z;
                float v3 = acc[m][nt][3] + bs.w;
                if (RELU) {
                    v0 = (v0 >= 0.f) ? v0 : NEG * v0;
                    v1 = (v1 >= 0.f) ? v1 : NEG * v1;
                    v2 = (v2 >= 0.f) ? v2 : NEG * v2;
                    v3 = (v3 >= 0.f) ? v3 : NEG * v3;
                }
                ushort4 o;
                o.x = f2bf(v0); o.y = f2bf(v1); o.z = f2bf(v2); o.w = f2bf(v3);
                *reinterpret_cast<ushort4*>(Out + (((size_t)(b * HH + y)) * WW + x) * OCOUT + oc0) = o;
            }
        }
    } else {
        if (lk == 0) {
#pragma unroll
            for (int nt = 0; nt < NT; nt++) {
                int x = n0 + nt * 16 + lx;
#pragma unroll
                for (int r = 0; r < 2; r++) {
                    size_t o = (((size_t)(b * 2 + r)) * HH + y) * WW + x;
                    fout[o] = acc[0][nt][r] + bias[r] + flow_up[o];
                }
            }
        }
    }
}

extern "C" void kernel_launch(void* const* d_in, const int* in_sizes, int n_in,
                              void* d_out, int out_size, void* d_ws, size_t ws_size,
                              hipStream_t stream) {
    const float* f1   = (const float*)d_in[0];
    const float* f2   = (const float*)d_in[1];
    const float* flow = (const float*)d_in[2];
    const float* w1   = (const float*)d_in[3];
    const float* b1   = (const float*)d_in[4];
    const float* w2   = (const float*)d_in[5];
    const float* b2   = (const float*)d_in[6];
    const float* w3   = (const float*)d_in[7];
    const float* b3   = (const float*)d_in[8];
    float* out = (float*)d_out;

    char* ws = (char*)d_ws;
    const size_t SZ_FLOWUP = (size_t)BB * 2 * HW * 4;          // 1.0 MB
    const size_t SZ_CT     = (size_t)BB * HW * 64 * 2;         // 16.8 MB
    const size_t SZ_WT1    = (size_t)9 * 64 * 64 * 2;
    const size_t SZ_WT2    = (size_t)9 * 32 * 64 * 2;
    const size_t SZ_WT3    = (size_t)25 * 16 * 32 * 2;
    const size_t SZ_BUF    = (size_t)BB * HW * CC * 2;         // 33.5 MB

    float*  flow_up = (float*)ws;                         ws += SZ_FLOWUP;
    ushort* Ct      = (ushort*)ws;                        ws += SZ_CT;
    ushort* Wt1     = (ushort*)ws;                        ws += SZ_WT1;
    ushort* Wt2     = (ushort*)ws;                        ws += SZ_WT2;
    ushort* Wt3     = (ushort*)ws;                        ws += SZ_WT3;
    ushort* f2wg8   = (ushort*)ws;                        ws += SZ_BUF;   // bufB
    ushort* bufA    = (ushort*)ws;                        // f2cl -> f1g8 -> h1/h2
    ushort* f2cl    = bufA;
    ushort* f1g8    = bufA;
    ushort* h1      = bufA;
    ushort* h2      = (ushort*)((char*)bufA + (size_t)BB * HW * 64 * 2);

    k_prep_w<49, 64, 64, 64, 3><<<dim3((9 * 64 * 64 + 255) / 256), dim3(256), 0, stream>>>(w1, Wt1);
    k_prep_w<64, 64, 32, 32, 3><<<dim3((9 * 32 * 64 + 255) / 256), dim3(256), 0, stream>>>(w2, Wt2);
    k_prep_w<32, 32, 2, 16, 5><<<dim3((25 * 16 * 32 + 255) / 256), dim3(256), 0, stream>>>(w3, Wt3);

    k_flow_up<<<dim3(HH, 2, BB), dim3(WW), 0, stream>>>(flow, flow_up);
    k_prep_cl<<<dim3(2048), dim3(256), 0, stream>>>(f2, f2cl);
    k_warp2  <<<dim3(8192), dim3(256), 0, stream>>>(f2cl, flow_up, f2wg8);
    k_prep_f1<<<dim3(4096), dim3(256), 0, stream>>>(f1, f1g8);   // overwrites bufA (f2cl dead)
    k_corr_mfma<<<dim3(1024), dim3(512), 0, stream>>>(f1g8, f2wg8, Ct);

    // all convs: 1 row/block, 4 waves x NT=2 (32 px), full OC per wave -> 1024 blocks, 4096 waves
    k_conv_mfma<64, 64, 4, 2, 64, 3, 1, true,  false>
        <<<dim3(HH, BB), dim3(256), 0, stream>>>(Ct, Wt1, b1, h1, nullptr, nullptr);
    k_conv_mfma<64, 32, 2, 2, 32, 3, 1, true,  false>
        <<<dim3(HH, BB), dim3(256), 0, stream>>>(h1, Wt2, b2, h2, nullptr, nullptr);
    k_conv_mfma<32, 16, 1, 2, 2,  5, 2, false, true >
        <<<dim3(HH, BB), dim3(256), 0, stream>>>(h2, Wt3, b3, nullptr, flow_up, out);
}

// Round 13
// 131.199 us; speedup vs baseline: 1.5314x; 1.4759x over previous
//
#include <hip/hip_runtime.h>
#include <hip/hip_bf16.h>

#define BB 8
#define CC 128
#define HH 128
#define WW 128
#define HW (HH*WW)
#define MD 3
#define ND 49
#define WARP_WEIGHT 2.5f
#define NEG 0.1f

typedef __attribute__((ext_vector_type(8))) short bf16x8;
typedef __attribute__((ext_vector_type(4))) float f32x4;

__device__ inline ushort f2bf(float f) {
    __hip_bfloat16 h = __float2bfloat16(f);
    return *reinterpret_cast<ushort*>(&h);
}
__device__ inline float bf2f(short s) {
    return __uint_as_float(((uint)(ushort)s) << 16);
}

// g8 layout: F[b][y][g][x][8] ushort, g = c/8
#define G8_IDX(b, y, g) ((((size_t)((b) * HH + (y)) * 16) + (g)) * (WW * 8))

// ---------------- flow upsample (bilinear x2, align_corners=False) ----------------
__global__ void k_flow_up(const float* __restrict__ flow, float* __restrict__ flow_up) {
    const int x = threadIdx.x;
    const int y = blockIdx.x;
    const int c = blockIdx.y;
    const int b = blockIdx.z;
    const int Hs = 64, Ws = 64;
    float sy = (y + 0.5f) * 0.5f - 0.5f;
    float sx = (x + 0.5f) * 0.5f - 0.5f;
    float y0f = floorf(sy), x0f = floorf(sx);
    int y0 = (int)y0f, x0 = (int)x0f;
    float wy = sy - y0f, wx = sx - x0f;
    int y0c = min(max(y0, 0), Hs - 1), y1c = min(max(y0 + 1, 0), Hs - 1);
    int x0c = min(max(x0, 0), Ws - 1), x1c = min(max(x0 + 1, 0), Ws - 1);
    const float* src = flow + ((size_t)(b * 2 + c)) * Hs * Ws;
    float v00 = src[y0c * Ws + x0c], v01 = src[y0c * Ws + x1c];
    float v10 = src[y1c * Ws + x0c], v11 = src[y1c * Ws + x1c];
    float v = v00 * (1.f - wx) * (1.f - wy) + v01 * wx * (1.f - wy)
            + v10 * (1.f - wx) * wy + v11 * wx * wy;
    flow_up[((size_t)(b * 2 + c) * HH + y) * WW + x] = v;
}

// ---------------- f2 planar f32 -> channel-last bf16 [b][y][x][128] via LDS ----------------
__global__ __launch_bounds__(256) void k_prep_cl(const float* __restrict__ src,
                                                 ushort* __restrict__ dstcl) {
    __shared__ ushort lds[128][68];
    const int y = blockIdx.x & 127;
    const int b = (blockIdx.x >> 7) & 7;
    const int chunk = blockIdx.x >> 10;      // 0..1 (64 channels each)
    {
        const int x = threadIdx.x & 127;
        const int cg = threadIdx.x >> 7;     // 0..1 -> 32 ch each
        const int c0 = chunk * 64 + cg * 32;
        const float* s = src + ((size_t)b * CC + c0) * HW + y * WW + x;
#pragma unroll
        for (int j4 = 0; j4 < 8; j4++) {
            ushort t[4];
#pragma unroll
            for (int u = 0; u < 4; u++) t[u] = f2bf(s[(size_t)(j4 * 4 + u) * HW]);
            *reinterpret_cast<uint2*>(&lds[x][cg * 32 + j4 * 4]) =
                *reinterpret_cast<const uint2*>(t);
        }
    }
    __syncthreads();
    {
        const int xw = threadIdx.x >> 1;
        const int h = threadIdx.x & 1;
        ushort* d = dstcl + (((size_t)(b * HH + y)) * WW + xw) * CC + chunk * 64 + h * 32;
#pragma unroll
        for (int i = 0; i < 8; i++)
            *reinterpret_cast<uint2*>(d + i * 4) =
                *reinterpret_cast<const uint2*>(&lds[xw][h * 32 + i * 4]);
    }
}

// ---------------- backward warp: CL gather -> g8 store ----------------
__global__ __launch_bounds__(256) void k_warp2(const ushort* __restrict__ f2cl,
                                               const float* __restrict__ flow_up,
                                               ushort* __restrict__ f2wg8) {
    const int bid = blockIdx.x;          // 8192
    const int k = bid & 7;               // XCD band
    const int t = bid >> 3;              // 0..1023
    const int xs = t & 7;
    const int y  = k * 16 + ((t >> 3) & 15);
    const int b  = t >> 7;
    const int p  = threadIdx.x >> 4;     // pixel in block (0..15)
    const int g  = threadIdx.x & 15;     // channel group (8 ch)
    const int x  = xs * 16 + p;

    const float fx = flow_up[((size_t)(b * 2 + 0) * HH + y) * WW + x] * WARP_WEIGHT;
    const float fy = flow_up[((size_t)(b * 2 + 1) * HH + y) * WW + x] * WARP_WEIGHT;
    const float sx = (float)x + fx;
    const float sy = (float)y + fy;
    float x0f = floorf(sx), y0f = floorf(sy);
    int x0 = (int)x0f, y0 = (int)y0f;
    float wx = sx - x0f, wy = sy - y0f;
    int x0c = min(max(x0, 0), WW - 1), x1c = min(max(x0 + 1, 0), WW - 1);
    int y0c = min(max(y0, 0), HH - 1), y1c = min(max(y0 + 1, 0), HH - 1);
    bool vx0 = (x0 >= 0) & (x0 < WW);
    bool vx1 = (x0 + 1 >= 0) & (x0 + 1 < WW);
    bool vy0 = (y0 >= 0) & (y0 < HH);
    bool vy1 = (y0 + 1 >= 0) & (y0 + 1 < HH);
    float w00 = (vx0 && vy0) ? (1.f - wx) * (1.f - wy) : 0.f;
    float w01 = (vx1 && vy0) ? wx * (1.f - wy) : 0.f;
    float w10 = (vx0 && vy1) ? (1.f - wx) * wy : 0.f;
    float w11 = (vx1 && vy1) ? wx * wy : 0.f;

    const ushort* base = f2cl + (size_t)b * HW * CC + (size_t)g * 8;
    bf16x8 t00 = *reinterpret_cast<const bf16x8*>(base + ((size_t)y0c * WW + x0c) * CC);
    bf16x8 t01 = *reinterpret_cast<const bf16x8*>(base + ((size_t)y0c * WW + x1c) * CC);
    bf16x8 t10 = *reinterpret_cast<const bf16x8*>(base + ((size_t)y1c * WW + x0c) * CC);
    bf16x8 t11 = *reinterpret_cast<const bf16x8*>(base + ((size_t)y1c * WW + x1c) * CC);

    ushort o[8];
#pragma unroll
    for (int j = 0; j < 8; j++) {
        float v = w00 * bf2f(t00[j]) + w01 * bf2f(t01[j])
                + w10 * bf2f(t10[j]) + w11 * bf2f(t11[j]);
        o[j] = f2bf(v);
    }
    *reinterpret_cast<uint4*>(f2wg8 + G8_IDX(b, y, g) + x * 8) =
        *reinterpret_cast<const uint4*>(o);
}

// ---------------- f1 planar f32 -> g8 bf16 ----------------
__global__ __launch_bounds__(256) void k_prep_f1(const float* __restrict__ f1,
                                                 ushort* __restrict__ f1g8) {
    const int bid = blockIdx.x;            // 4096
    const int y = bid & 127;
    const int b = (bid >> 7) & 7;
    const int chunk = bid >> 10;           // 0..3
    const int x  = threadIdx.x & 127;
    const int cg = threadIdx.x >> 7;
    const int c0 = chunk * 32 + cg * 16;
    const float* src = f1 + ((size_t)b * CC + c0) * HW + y * WW + x;
#pragma unroll
    for (int gi = 0; gi < 2; gi++) {
        ushort tmp[8];
#pragma unroll
        for (int j = 0; j < 8; j++) tmp[j] = f2bf(src[(size_t)(gi * 8 + j) * HW]);
        *reinterpret_cast<uint4*>(f1g8 + G8_IDX(b, y, (c0 >> 3) + gi) + x * 8) =
            *reinterpret_cast<const uint4*>(tmp);
    }
}

// ---------------- MFMA cost volume v4: XCD-banded grid + LDS-staged output + B prefetch ----
__global__ __launch_bounds__(512) void k_corr_mfma(const ushort* __restrict__ f1g8,
                                                   const ushort* __restrict__ f2g8,
                                                   ushort* __restrict__ Ct) {
    __shared__ ushort cstage[128][68];     // 17.4 KB
    const int b  = blockIdx.x & 7;
    const int y  = blockIdx.x >> 3;
    const int w  = threadIdx.x >> 6;       // x-tile 0..7
    const int l  = threadIdx.x & 63;
    const int lx = l & 15;
    const int lk = l >> 4;
    const int xa0 = w * 16;

    {
        const int px = threadIdx.x >> 2;
        const int part = threadIdx.x & 3;
        uint2 z = {0u, 0u};
        *reinterpret_cast<uint2*>(&cstage[px][48 + part * 4]) = z;
    }
    __syncthreads();

    bf16x8 afr[4];
#pragma unroll
    for (int kk = 0; kk < 4; kk++)
        afr[kk] = *reinterpret_cast<const bf16x8*>(
            f1g8 + G8_IDX(b, y, kk * 4 + lk) + (xa0 + lx) * 8);

    const int xb0 = xa0 - 3 + lx;
    const int xb1 = xa0 + 13 + lx;
    const float scale = 1.f / (float)CC;

    bf16x8 bb[2][8];
    auto load_b = [&](int dy, int buf) {
        const int yy = y + dy - MD;
        const bool yv = (unsigned)yy < (unsigned)HH;
#pragma unroll
        for (int kk = 0; kk < 4; kk++) {
            const ushort* grp = f2g8 + G8_IDX(b, yy, kk * 4 + lk);
            bf16x8 b0 = {}, b1 = {};
            if (yv && (unsigned)xb0 < (unsigned)WW)
                b0 = *reinterpret_cast<const bf16x8*>(grp + xb0 * 8);
            if (yv && (unsigned)xb1 < (unsigned)WW)
                b1 = *reinterpret_cast<const bf16x8*>(grp + xb1 * 8);
            bb[buf][kk * 2 + 0] = b0;
            bb[buf][kk * 2 + 1] = b1;
        }
    };

    load_b(0, 0);
#pragma unroll
    for (int dy = 0; dy < 7; dy++) {
        if (dy + 1 < 7) load_b(dy + 1, (dy + 1) & 1);
        f32x4 acc0 = (f32x4)(0.f), acc1 = (f32x4)(0.f);
#pragma unroll
        for (int kk = 0; kk < 4; kk++) {
            acc0 = __builtin_amdgcn_mfma_f32_16x16x32_bf16(
                afr[kk], bb[dy & 1][kk * 2 + 0], acc0, 0, 0, 0);
            acc1 = __builtin_amdgcn_mfma_f32_16x16x32_bf16(
                afr[kk], bb[dy & 1][kk * 2 + 1], acc1, 0, 0, 0);
        }
#pragma unroll
        for (int r = 0; r < 4; r++) {
            const int i = lk * 4 + r;
            const int d0 = lx - i;
            if (d0 >= 0 && d0 <= 6)
                cstage[xa0 + i][dy * 7 + d0] = f2bf(acc0[r] * scale);
            const int d1 = lx - i + 16;
            if (d1 >= 0 && d1 <= 6)
                cstage[xa0 + i][dy * 7 + d1] = f2bf(acc1[r] * scale);
        }
    }
    __syncthreads();

    {
        const int px = threadIdx.x >> 2;
        const int part = threadIdx.x & 3;
        ushort* dst = Ct + (((size_t)(b * HH + y)) * WW + px) * 64 + part * 16;
        uint2 t0 = *reinterpret_cast<const uint2*>(&cstage[px][part * 16 + 0]);
        uint2 t1 = *reinterpret_cast<const uint2*>(&cstage[px][part * 16 + 4]);
        uint2 t2 = *reinterpret_cast<const uint2*>(&cstage[px][part * 16 + 8]);
        uint2 t3 = *reinterpret_cast<const uint2*>(&cstage[px][part * 16 + 12]);
        uint4 v0; v0.x = t0.x; v0.y = t0.y; v0.z = t1.x; v0.w = t1.y;
        uint4 v1; v1.x = t2.x; v1.y = t2.y; v1.z = t3.x; v1.w = t3.y;
        *reinterpret_cast<uint4*>(dst) = v0;
        *reinterpret_cast<uint4*>(dst + 8) = v1;
    }
}

// ------- weight prep v2: w[OC][IC][K][K] -> Wt[t = tap*NCH+ch][lk][OCP][8] bf16 -------
// element (oc, c=ch*32+lk*8+j) at ((t*4+lk)*OCP + oc)*8 + j  -> wave A-load is contiguous
template<int IC, int ICP, int OC, int OCP, int KK>
__global__ void k_prep_w2(const float* __restrict__ w, ushort* __restrict__ Wt) {
    constexpr int NCH = ICP / 32;
    int e = blockIdx.x * 256 + threadIdx.x;
    const int total = KK * KK * NCH * 4 * OCP * 8;
    if (e >= total) return;
    int j  = e & 7;
    int oc = (e >> 3) % OCP;
    int lk = (e / (8 * OCP)) & 3;
    int t  = e / (8 * OCP * 4);
    int ch = t % NCH;
    int tap = t / NCH;
    int kh = tap / KK, kw = tap % KK;
    int c = ch * 32 + lk * 8 + j;
    float v = 0.f;
    if (oc < OC && c < IC) v = w[((oc * IC + c) * KK + kh) * KK + kw];
    Wt[e] = f2bf(v);
}

// ---------------- conv v4: LDS-staged input rows + swizzled ds_read + MFMA ----------------
// 512 thr = 8 waves; 2 output rows/block; stage KK+1 input rows in LDS (XOR-swizzled).
// Wave w: row wr=w>>2, px quarter wq=w&3 (NT=2 -> 32 px). A from contiguous Wt (1 tap ahead).
template<int ICP, int OCP, int MT, int NT, int OCOUT, int KK, int PAD, bool RELU, bool LAST>
__global__ __launch_bounds__(512, 4) void k_conv_lds(
    const ushort* __restrict__ In, const ushort* __restrict__ Wt,
    const float* __restrict__ bias, ushort* __restrict__ Out,
    const float* __restrict__ flow_up, float* __restrict__ fout)
{
    constexpr int NCH = ICP / 32;
    constexpr int NTAP = KK * KK * NCH;
    constexpr int ROWB = ICP * 2;               // bytes per pixel row element
    constexpr int ROWBYTES = WW * ROWB;         // 16 KB (ICP=64) / 8 KB (ICP=32)
    constexpr int NROWS = KK + 1;
    constexpr int SLAB = NROWS * ROWBYTES;
    constexpr int LOG2ROWB = (ICP == 64) ? 7 : 6;
    constexpr int SWZM = (ICP == 64) ? 7 : 3;
    constexpr int ITER = SLAB / (512 * 16);

    __shared__ __align__(16) char slds[SLAB];

    const int y0 = blockIdx.x * 2;
    const int b = blockIdx.y;
    const char* inb = (const char*)(In + (size_t)b * HH * WW * ICP);

    // ---- stage rows [y0-PAD .. y0-PAD+NROWS-1] (clamped) with XOR swizzle ----
#pragma unroll
    for (int it = 0; it < ITER; it++) {
        int L = it * 512 * 16 + threadIdx.x * 16;
        int r = L / ROWBYTES;
        int Lr = L % ROWBYTES;
        int grow = min(max(y0 - PAD + r, 0), HH - 1);
        uint4 v = *reinterpret_cast<const uint4*>(inb + (size_t)grow * ROWBYTES + Lr);
        int dst = r * ROWBYTES + (Lr ^ (((Lr >> LOG2ROWB) & SWZM) << 4));
        *reinterpret_cast<uint4*>(&slds[dst]) = v;
    }
    __syncthreads();

    const int w = threadIdx.x >> 6;
    const int l = threadIdx.x & 63;
    const int lx = l & 15;
    const int lk = l >> 4;
    const int wr = w >> 2;
    const int wq = w & 3;
    const int y = y0 + wr;
    const int n0 = wq * (16 * NT);

    f32x4 acc[MT][NT];
#pragma unroll
    for (int m = 0; m < MT; m++)
#pragma unroll
        for (int nt = 0; nt < NT; nt++) acc[m][nt] = (f32x4)(0.f);

    bf16x8 abuf[2][MT];
    auto load_a = [&](int t, int buf) {
#pragma unroll
        for (int m = 0; m < MT; m++)
            abuf[buf][m] = *reinterpret_cast<const bf16x8*>(
                Wt + ((size_t)(t * 4 + lk) * OCP + m * 16 + lx) * 8);
    };

    load_a(0, 0);
#pragma unroll
    for (int t = 0; t < NTAP; t++) {
        if (t + 1 < NTAP) load_a(t + 1, (t + 1) & 1);
        const int kh = t / (KK * NCH);
        const int kw = (t / NCH) % KK;
        const int ch = t % NCH;
        const int slab_r = wr + kh;
        const int yy = y + kh - PAD;
        const bool yv = (unsigned)yy < (unsigned)HH;
        bf16x8 bfr[NT];
#pragma unroll
        for (int nt = 0; nt < NT; nt++) {
            int xx = n0 + nt * 16 + lx + kw - PAD;
            int xc = min(max(xx, 0), WW - 1);
            int off = slab_r * ROWBYTES
                    + ((xc * ROWB + (ch * 4 + lk) * 16) ^ ((xc & SWZM) << 4));
            bf16x8 v = *reinterpret_cast<const bf16x8*>(&slds[off]);
            bool valid = yv && ((unsigned)xx < (unsigned)WW);
            bfr[nt] = valid ? v : (bf16x8){};
        }
#pragma unroll
        for (int nt = 0; nt < NT; nt++)
#pragma unroll
            for (int m = 0; m < MT; m++)
                acc[m][nt] = __builtin_amdgcn_mfma_f32_16x16x32_bf16(
                    abuf[t & 1][m], bfr[nt], acc[m][nt], 0, 0, 0);
    }

    if (!LAST) {
#pragma unroll
        for (int m = 0; m < MT; m++) {
            const int oc0 = m * 16 + lk * 4;
            float4 bs = *reinterpret_cast<const float4*>(bias + oc0);
#pragma unroll
            for (int nt = 0; nt < NT; nt++) {
                int x = n0 + nt * 16 + lx;
                float v0 = acc[m][nt][0] + bs.x;
                float v1 = acc[m][nt][1] + bs.y;
                float v2 = acc[m][nt][2] + bs.z;
                float v3 = acc[m][nt][3] + bs.w;
                if (RELU) {
                    v0 = (v0 >= 0.f) ? v0 : NEG * v0;
                    v1 = (v1 >= 0.f) ? v1 : NEG * v1;
                    v2 = (v2 >= 0.f) ? v2 : NEG * v2;
                    v3 = (v3 >= 0.f) ? v3 : NEG * v3;
                }
                ushort4 o;
                o.x = f2bf(v0); o.y = f2bf(v1); o.z = f2bf(v2); o.w = f2bf(v3);
                *reinterpret_cast<ushort4*>(Out + (((size_t)(b * HH + y)) * WW + x) * OCOUT + oc0) = o;
            }
        }
    } else {
        if (lk == 0) {
#pragma unroll
            for (int nt = 0; nt < NT; nt++) {
                int x = n0 + nt * 16 + lx;
#pragma unroll
                for (int r = 0; r < 2; r++) {
                    size_t o = (((size_t)(b * 2 + r)) * HH + y) * WW + x;
                    fout[o] = acc[0][nt][r] + bias[r] + flow_up[o];
                }
            }
        }
    }
}

extern "C" void kernel_launch(void* const* d_in, const int* in_sizes, int n_in,
                              void* d_out, int out_size, void* d_ws, size_t ws_size,
                              hipStream_t stream) {
    const float* f1   = (const float*)d_in[0];
    const float* f2   = (const float*)d_in[1];
    const float* flow = (const float*)d_in[2];
    const float* w1   = (const float*)d_in[3];
    const float* b1   = (const float*)d_in[4];
    const float* w2   = (const float*)d_in[5];
    const float* b2   = (const float*)d_in[6];
    const float* w3   = (const float*)d_in[7];
    const float* b3   = (const float*)d_in[8];
    float* out = (float*)d_out;

    char* ws = (char*)d_ws;
    const size_t SZ_FLOWUP = (size_t)BB * 2 * HW * 4;          // 1.0 MB
    const size_t SZ_CT     = (size_t)BB * HW * 64 * 2;         // 16.8 MB
    const size_t SZ_WT1    = (size_t)9 * 2 * 4 * 64 * 8 * 2;   // 73.7 KB
    const size_t SZ_WT2    = (size_t)9 * 2 * 4 * 32 * 8 * 2;   // 36.9 KB
    const size_t SZ_WT3    = (size_t)25 * 1 * 4 * 16 * 8 * 2;  // 25.6 KB
    const size_t SZ_BUF    = (size_t)BB * HW * CC * 2;         // 33.5 MB

    float*  flow_up = (float*)ws;                         ws += SZ_FLOWUP;
    ushort* Ct      = (ushort*)ws;                        ws += SZ_CT;
    ushort* Wt1     = (ushort*)ws;                        ws += SZ_WT1;
    ushort* Wt2     = (ushort*)ws;                        ws += SZ_WT2;
    ushort* Wt3     = (ushort*)ws;                        ws += SZ_WT3;
    ushort* f2wg8   = (ushort*)ws;                        ws += SZ_BUF;   // bufB
    ushort* bufA    = (ushort*)ws;                        // f2cl -> f1g8 -> h1/h2
    ushort* f2cl    = bufA;
    ushort* f1g8    = bufA;
    ushort* h1      = bufA;
    ushort* h2      = (ushort*)((char*)bufA + (size_t)BB * HW * 64 * 2);

    k_prep_w2<49, 64, 64, 64, 3><<<dim3((9 * 2 * 4 * 64 * 8 + 255) / 256), dim3(256), 0, stream>>>(w1, Wt1);
    k_prep_w2<64, 64, 32, 32, 3><<<dim3((9 * 2 * 4 * 32 * 8 + 255) / 256), dim3(256), 0, stream>>>(w2, Wt2);
    k_prep_w2<32, 32, 2, 16, 5><<<dim3((25 * 1 * 4 * 16 * 8 + 255) / 256), dim3(256), 0, stream>>>(w3, Wt3);

    k_flow_up<<<dim3(HH, 2, BB), dim3(WW), 0, stream>>>(flow, flow_up);
    k_prep_cl<<<dim3(2048), dim3(256), 0, stream>>>(f2, f2cl);
    k_warp2  <<<dim3(8192), dim3(256), 0, stream>>>(f2cl, flow_up, f2wg8);
    k_prep_f1<<<dim3(4096), dim3(256), 0, stream>>>(f1, f1g8);   // overwrites bufA (f2cl dead)
    k_corr_mfma<<<dim3(1024), dim3(512), 0, stream>>>(f1g8, f2wg8, Ct);

    k_conv_lds<64, 64, 4, 2, 64, 3, 1, true,  false>
        <<<dim3(HH / 2, BB), dim3(512), 0, stream>>>(Ct, Wt1, b1, h1, nullptr, nullptr);
    k_conv_lds<64, 32, 2, 2, 32, 3, 1, true,  false>
        <<<dim3(HH / 2, BB), dim3(512), 0, stream>>>(h1, Wt2, b2, h2, nullptr, nullptr);
    k_conv_lds<32, 16, 1, 2, 2,  5, 2, false, true >
        <<<dim3(HH / 2, BB), dim3(512), 0, stream>>>(h2, Wt3, b3, nullptr, flow_up, out);
}

// Round 14
// 119.322 us; speedup vs baseline: 1.6838x; 1.0995x over previous
//
#include <hip/hip_runtime.h>
#include <hip/hip_bf16.h>

#define BB 8
#define CC 128
#define HH 128
#define WW 128
#define HW (HH*WW)
#define MD 3
#define ND 49
#define WARP_WEIGHT 2.5f
#define NEG 0.1f

typedef __attribute__((ext_vector_type(8))) short bf16x8;
typedef __attribute__((ext_vector_type(4))) float f32x4;

__device__ inline ushort f2bf(float f) {
    __hip_bfloat16 h = __float2bfloat16(f);
    return *reinterpret_cast<ushort*>(&h);
}
__device__ inline float bf2f(short s) {
    return __uint_as_float(((uint)(ushort)s) << 16);
}

// g8 layout: F[b][y][g][x][8] ushort, g = c/8
#define G8_IDX(b, y, g) ((((size_t)((b) * HH + (y)) * 16) + (g)) * (WW * 8))

// ---------------- flow upsample (bilinear x2, align_corners=False) ----------------
__global__ void k_flow_up(const float* __restrict__ flow, float* __restrict__ flow_up) {
    const int x = threadIdx.x;
    const int y = blockIdx.x;
    const int c = blockIdx.y;
    const int b = blockIdx.z;
    const int Hs = 64, Ws = 64;
    float sy = (y + 0.5f) * 0.5f - 0.5f;
    float sx = (x + 0.5f) * 0.5f - 0.5f;
    float y0f = floorf(sy), x0f = floorf(sx);
    int y0 = (int)y0f, x0 = (int)x0f;
    float wy = sy - y0f, wx = sx - x0f;
    int y0c = min(max(y0, 0), Hs - 1), y1c = min(max(y0 + 1, 0), Hs - 1);
    int x0c = min(max(x0, 0), Ws - 1), x1c = min(max(x0 + 1, 0), Ws - 1);
    const float* src = flow + ((size_t)(b * 2 + c)) * Hs * Ws;
    float v00 = src[y0c * Ws + x0c], v01 = src[y0c * Ws + x1c];
    float v10 = src[y1c * Ws + x0c], v11 = src[y1c * Ws + x1c];
    float v = v00 * (1.f - wx) * (1.f - wy) + v01 * wx * (1.f - wy)
            + v10 * (1.f - wx) * wy + v11 * wx * wy;
    flow_up[((size_t)(b * 2 + c) * HH + y) * WW + x] = v;
}

// ---------------- f2 planar f32 -> channel-last bf16 [b][y][x][128] via LDS ----------------
__global__ __launch_bounds__(256) void k_prep_cl(const float* __restrict__ src,
                                                 ushort* __restrict__ dstcl) {
    __shared__ ushort lds[128][68];
    const int y = blockIdx.x & 127;
    const int b = (blockIdx.x >> 7) & 7;
    const int chunk = blockIdx.x >> 10;      // 0..1 (64 channels each)
    {
        const int x = threadIdx.x & 127;
        const int cg = threadIdx.x >> 7;     // 0..1 -> 32 ch each
        const int c0 = chunk * 64 + cg * 32;
        const float* s = src + ((size_t)b * CC + c0) * HW + y * WW + x;
#pragma unroll
        for (int j4 = 0; j4 < 8; j4++) {
            ushort t[4];
#pragma unroll
            for (int u = 0; u < 4; u++) t[u] = f2bf(s[(size_t)(j4 * 4 + u) * HW]);
            *reinterpret_cast<uint2*>(&lds[x][cg * 32 + j4 * 4]) =
                *reinterpret_cast<const uint2*>(t);
        }
    }
    __syncthreads();
    {
        const int xw = threadIdx.x >> 1;
        const int h = threadIdx.x & 1;
        ushort* d = dstcl + (((size_t)(b * HH + y)) * WW + xw) * CC + chunk * 64 + h * 32;
#pragma unroll
        for (int i = 0; i < 8; i++)
            *reinterpret_cast<uint2*>(d + i * 4) =
                *reinterpret_cast<const uint2*>(&lds[xw][h * 32 + i * 4]);
    }
}

// ---------------- backward warp: CL gather -> g8 store ----------------
__global__ __launch_bounds__(256) void k_warp2(const ushort* __restrict__ f2cl,
                                               const float* __restrict__ flow_up,
                                               ushort* __restrict__ f2wg8) {
    const int bid = blockIdx.x;          // 8192
    const int k = bid & 7;               // XCD band
    const int t = bid >> 3;              // 0..1023
    const int xs = t & 7;
    const int y  = k * 16 + ((t >> 3) & 15);
    const int b  = t >> 7;
    const int p  = threadIdx.x >> 4;     // pixel in block (0..15)
    const int g  = threadIdx.x & 15;     // channel group (8 ch)
    const int x  = xs * 16 + p;

    const float fx = flow_up[((size_t)(b * 2 + 0) * HH + y) * WW + x] * WARP_WEIGHT;
    const float fy = flow_up[((size_t)(b * 2 + 1) * HH + y) * WW + x] * WARP_WEIGHT;
    const float sx = (float)x + fx;
    const float sy = (float)y + fy;
    float x0f = floorf(sx), y0f = floorf(sy);
    int x0 = (int)x0f, y0 = (int)y0f;
    float wx = sx - x0f, wy = sy - y0f;
    int x0c = min(max(x0, 0), WW - 1), x1c = min(max(x0 + 1, 0), WW - 1);
    int y0c = min(max(y0, 0), HH - 1), y1c = min(max(y0 + 1, 0), HH - 1);
    bool vx0 = (x0 >= 0) & (x0 < WW);
    bool vx1 = (x0 + 1 >= 0) & (x0 + 1 < WW);
    bool vy0 = (y0 >= 0) & (y0 < HH);
    bool vy1 = (y0 + 1 >= 0) & (y0 + 1 < HH);
    float w00 = (vx0 && vy0) ? (1.f - wx) * (1.f - wy) : 0.f;
    float w01 = (vx1 && vy0) ? wx * (1.f - wy) : 0.f;
    float w10 = (vx0 && vy1) ? (1.f - wx) * wy : 0.f;
    float w11 = (vx1 && vy1) ? wx * wy : 0.f;

    const ushort* base = f2cl + (size_t)b * HW * CC + (size_t)g * 8;
    bf16x8 t00 = *reinterpret_cast<const bf16x8*>(base + ((size_t)y0c * WW + x0c) * CC);
    bf16x8 t01 = *reinterpret_cast<const bf16x8*>(base + ((size_t)y0c * WW + x1c) * CC);
    bf16x8 t10 = *reinterpret_cast<const bf16x8*>(base + ((size_t)y1c * WW + x0c) * CC);
    bf16x8 t11 = *reinterpret_cast<const bf16x8*>(base + ((size_t)y1c * WW + x1c) * CC);

    ushort o[8];
#pragma unroll
    for (int j = 0; j < 8; j++) {
        float v = w00 * bf2f(t00[j]) + w01 * bf2f(t01[j])
                + w10 * bf2f(t10[j]) + w11 * bf2f(t11[j]);
        o[j] = f2bf(v);
    }
    *reinterpret_cast<uint4*>(f2wg8 + G8_IDX(b, y, g) + x * 8) =
        *reinterpret_cast<const uint4*>(o);
}

// ---------------- MFMA cost volume v5: fused f1 transpose (planar f32 in) ----------------
// grid: 1024 blocks = b(8, XCD-banded) x y(128). Block: 8 waves = 8 x-tiles, 1 row.
// Stages f1 row y in LDS (g8 layout, conflict-free), B prefetch dbuf, LDS-staged Ct out.
__global__ __launch_bounds__(512) void k_corr_mfma(const float* __restrict__ f1,
                                                   const ushort* __restrict__ f2g8,
                                                   ushort* __restrict__ Ct) {
    __shared__ __align__(16) ushort af1[16][128][8];   // 32 KB, g8 layout of f1 row
    __shared__ ushort cstage[128][68];                 // 17.4 KB
    const int b  = blockIdx.x & 7;
    const int y  = blockIdx.x >> 3;
    const int w  = threadIdx.x >> 6;       // x-tile 0..7
    const int l  = threadIdx.x & 63;
    const int lx = l & 15;
    const int lk = l >> 4;
    const int xa0 = w * 16;

    // ---- stage f1[b][:][y][:] -> af1 (g8) ; also zero cstage ch 48..63 ----
    {
        const int x = threadIdx.x & 127;
        const int half = threadIdx.x >> 7;          // 0..3 -> 32 ch each
        const int c0 = half * 32;
        const float* src = f1 + ((size_t)b * CC + c0) * HW + y * WW + x;
#pragma unroll
        for (int gi = 0; gi < 4; gi++) {
            ushort tmp[8];
#pragma unroll
            for (int j = 0; j < 8; j++) tmp[j] = f2bf(src[(size_t)(gi * 8 + j) * HW]);
            *reinterpret_cast<uint4*>(&af1[(c0 >> 3) + gi][x][0]) =
                *reinterpret_cast<const uint4*>(tmp);
        }
        const int px = threadIdx.x >> 2;
        const int part = threadIdx.x & 3;
        uint2 z = {0u, 0u};
        *reinterpret_cast<uint2*>(&cstage[px][48 + part * 4]) = z;
    }
    __syncthreads();

    bf16x8 afr[4];
#pragma unroll
    for (int kk = 0; kk < 4; kk++)
        afr[kk] = *reinterpret_cast<const bf16x8*>(&af1[kk * 4 + lk][xa0 + lx][0]);

    const int xb0 = xa0 - 3 + lx;
    const int xb1 = xa0 + 13 + lx;
    const float scale = 1.f / (float)CC;

    bf16x8 bb[2][8];
    auto load_b = [&](int dy, int buf) {
        const int yy = y + dy - MD;
        const bool yv = (unsigned)yy < (unsigned)HH;
#pragma unroll
        for (int kk = 0; kk < 4; kk++) {
            const ushort* grp = f2g8 + G8_IDX(b, yy, kk * 4 + lk);
            bf16x8 b0 = {}, b1 = {};
            if (yv && (unsigned)xb0 < (unsigned)WW)
                b0 = *reinterpret_cast<const bf16x8*>(grp + xb0 * 8);
            if (yv && (unsigned)xb1 < (unsigned)WW)
                b1 = *reinterpret_cast<const bf16x8*>(grp + xb1 * 8);
            bb[buf][kk * 2 + 0] = b0;
            bb[buf][kk * 2 + 1] = b1;
        }
    };

    load_b(0, 0);
#pragma unroll
    for (int dy = 0; dy < 7; dy++) {
        if (dy + 1 < 7) load_b(dy + 1, (dy + 1) & 1);
        f32x4 acc0 = (f32x4)(0.f), acc1 = (f32x4)(0.f);
#pragma unroll
        for (int kk = 0; kk < 4; kk++) {
            acc0 = __builtin_amdgcn_mfma_f32_16x16x32_bf16(
                afr[kk], bb[dy & 1][kk * 2 + 0], acc0, 0, 0, 0);
            acc1 = __builtin_amdgcn_mfma_f32_16x16x32_bf16(
                afr[kk], bb[dy & 1][kk * 2 + 1], acc1, 0, 0, 0);
        }
#pragma unroll
        for (int r = 0; r < 4; r++) {
            const int i = lk * 4 + r;
            const int d0 = lx - i;
            if (d0 >= 0 && d0 <= 6)
                cstage[xa0 + i][dy * 7 + d0] = f2bf(acc0[r] * scale);
            const int d1 = lx - i + 16;
            if (d1 >= 0 && d1 <= 6)
                cstage[xa0 + i][dy * 7 + d1] = f2bf(acc1[r] * scale);
        }
    }
    __syncthreads();

    {
        const int px = threadIdx.x >> 2;
        const int part = threadIdx.x & 3;
        ushort* dst = Ct + (((size_t)(b * HH + y)) * WW + px) * 64 + part * 16;
        uint2 t0 = *reinterpret_cast<const uint2*>(&cstage[px][part * 16 + 0]);
        uint2 t1 = *reinterpret_cast<const uint2*>(&cstage[px][part * 16 + 4]);
        uint2 t2 = *reinterpret_cast<const uint2*>(&cstage[px][part * 16 + 8]);
        uint2 t3 = *reinterpret_cast<const uint2*>(&cstage[px][part * 16 + 12]);
        uint4 v0; v0.x = t0.x; v0.y = t0.y; v0.z = t1.x; v0.w = t1.y;
        uint4 v1; v1.x = t2.x; v1.y = t2.y; v1.z = t3.x; v1.w = t3.y;
        *reinterpret_cast<uint4*>(dst) = v0;
        *reinterpret_cast<uint4*>(dst + 8) = v1;
    }
}

// ------- weight prep v2: w[OC][IC][K][K] -> Wt[t = tap*NCH+ch][lk][OCP][8] bf16 -------
template<int IC, int ICP, int OC, int OCP, int KK>
__global__ void k_prep_w2(const float* __restrict__ w, ushort* __restrict__ Wt) {
    constexpr int NCH = ICP / 32;
    int e = blockIdx.x * 256 + threadIdx.x;
    const int total = KK * KK * NCH * 4 * OCP * 8;
    if (e >= total) return;
    int j  = e & 7;
    int oc = (e >> 3) % OCP;
    int lk = (e / (8 * OCP)) & 3;
    int t  = e / (8 * OCP * 4);
    int ch = t % NCH;
    int tap = t / NCH;
    int kh = tap / KK, kw = tap % KK;
    int c = ch * 32 + lk * 8 + j;
    float v = 0.f;
    if (oc < OC && c < IC) v = w[((oc * IC + c) * KK + kh) * KK + kw];
    Wt[e] = f2bf(v);
}

// ---------------- conv v4: LDS-staged input rows + swizzled ds_read + MFMA ----------------
template<int ICP, int OCP, int MT, int NT, int OCOUT, int KK, int PAD, bool RELU, bool LAST>
__global__ __launch_bounds__(512, 4) void k_conv_lds(
    const ushort* __restrict__ In, const ushort* __restrict__ Wt,
    const float* __restrict__ bias, ushort* __restrict__ Out,
    const float* __restrict__ flow_up, float* __restrict__ fout)
{
    constexpr int NCH = ICP / 32;
    constexpr int NTAP = KK * KK * NCH;
    constexpr int ROWB = ICP * 2;
    constexpr int ROWBYTES = WW * ROWB;
    constexpr int NROWS = KK + 1;
    constexpr int SLAB = NROWS * ROWBYTES;
    constexpr int LOG2ROWB = (ICP == 64) ? 7 : 6;
    constexpr int SWZM = (ICP == 64) ? 7 : 3;
    constexpr int ITER = SLAB / (512 * 16);

    __shared__ __align__(16) char slds[SLAB];

    const int y0 = blockIdx.x * 2;
    const int b = blockIdx.y;
    const char* inb = (const char*)(In + (size_t)b * HH * WW * ICP);

#pragma unroll
    for (int it = 0; it < ITER; it++) {
        int L = it * 512 * 16 + threadIdx.x * 16;
        int r = L / ROWBYTES;
        int Lr = L % ROWBYTES;
        int grow = min(max(y0 - PAD + r, 0), HH - 1);
        uint4 v = *reinterpret_cast<const uint4*>(inb + (size_t)grow * ROWBYTES + Lr);
        int dst = r * ROWBYTES + (Lr ^ (((Lr >> LOG2ROWB) & SWZM) << 4));
        *reinterpret_cast<uint4*>(&slds[dst]) = v;
    }
    __syncthreads();

    const int w = threadIdx.x >> 6;
    const int l = threadIdx.x & 63;
    const int lx = l & 15;
    const int lk = l >> 4;
    const int wr = w >> 2;
    const int wq = w & 3;
    const int y = y0 + wr;
    const int n0 = wq * (16 * NT);

    f32x4 acc[MT][NT];
#pragma unroll
    for (int m = 0; m < MT; m++)
#pragma unroll
        for (int nt = 0; nt < NT; nt++) acc[m][nt] = (f32x4)(0.f);

    bf16x8 abuf[2][MT];
    auto load_a = [&](int t, int buf) {
#pragma unroll
        for (int m = 0; m < MT; m++)
            abuf[buf][m] = *reinterpret_cast<const bf16x8*>(
                Wt + ((size_t)(t * 4 + lk) * OCP + m * 16 + lx) * 8);
    };

    load_a(0, 0);
#pragma unroll
    for (int t = 0; t < NTAP; t++) {
        if (t + 1 < NTAP) load_a(t + 1, (t + 1) & 1);
        const int kh = t / (KK * NCH);
        const int kw = (t / NCH) % KK;
        const int ch = t % NCH;
        const int slab_r = wr + kh;
        const int yy = y + kh - PAD;
        const bool yv = (unsigned)yy < (unsigned)HH;
        bf16x8 bfr[NT];
#pragma unroll
        for (int nt = 0; nt < NT; nt++) {
            int xx = n0 + nt * 16 + lx + kw - PAD;
            int xc = min(max(xx, 0), WW - 1);
            int off = slab_r * ROWBYTES
                    + ((xc * ROWB + (ch * 4 + lk) * 16) ^ ((xc & SWZM) << 4));
            bf16x8 v = *reinterpret_cast<const bf16x8*>(&slds[off]);
            bool valid = yv && ((unsigned)xx < (unsigned)WW);
            bfr[nt] = valid ? v : (bf16x8){};
        }
#pragma unroll
        for (int nt = 0; nt < NT; nt++)
#pragma unroll
            for (int m = 0; m < MT; m++)
                acc[m][nt] = __builtin_amdgcn_mfma_f32_16x16x32_bf16(
                    abuf[t & 1][m], bfr[nt], acc[m][nt], 0, 0, 0);
    }

    if (!LAST) {
#pragma unroll
        for (int m = 0; m < MT; m++) {
            const int oc0 = m * 16 + lk * 4;
            float4 bs = *reinterpret_cast<const float4*>(bias + oc0);
#pragma unroll
            for (int nt = 0; nt < NT; nt++) {
                int x = n0 + nt * 16 + lx;
                float v0 = acc[m][nt][0] + bs.x;
                float v1 = acc[m][nt][1] + bs.y;
                float v2 = acc[m][nt][2] + bs.z;
                float v3 = acc[m][nt][3] + bs.w;
                if (RELU) {
                    v0 = (v0 >= 0.f) ? v0 : NEG * v0;
                    v1 = (v1 >= 0.f) ? v1 : NEG * v1;
                    v2 = (v2 >= 0.f) ? v2 : NEG * v2;
                    v3 = (v3 >= 0.f) ? v3 : NEG * v3;
                }
                ushort4 o;
                o.x = f2bf(v0); o.y = f2bf(v1); o.z = f2bf(v2); o.w = f2bf(v3);
                *reinterpret_cast<ushort4*>(Out + (((size_t)(b * HH + y)) * WW + x) * OCOUT + oc0) = o;
            }
        }
    } else {
        if (lk == 0) {
#pragma unroll
            for (int nt = 0; nt < NT; nt++) {
                int x = n0 + nt * 16 + lx;
#pragma unroll
                for (int r = 0; r < 2; r++) {
                    size_t o = (((size_t)(b * 2 + r)) * HH + y) * WW + x;
                    fout[o] = acc[0][nt][r] + bias[r] + flow_up[o];
                }
            }
        }
    }
}

extern "C" void kernel_launch(void* const* d_in, const int* in_sizes, int n_in,
                              void* d_out, int out_size, void* d_ws, size_t ws_size,
                              hipStream_t stream) {
    const float* f1   = (const float*)d_in[0];
    const float* f2   = (const float*)d_in[1];
    const float* flow = (const float*)d_in[2];
    const float* w1   = (const float*)d_in[3];
    const float* b1   = (const float*)d_in[4];
    const float* w2   = (const float*)d_in[5];
    const float* b2   = (const float*)d_in[6];
    const float* w3   = (const float*)d_in[7];
    const float* b3   = (const float*)d_in[8];
    float* out = (float*)d_out;

    char* ws = (char*)d_ws;
    const size_t SZ_FLOWUP = (size_t)BB * 2 * HW * 4;          // 1.0 MB
    const size_t SZ_CT     = (size_t)BB * HW * 64 * 2;         // 16.8 MB
    const size_t SZ_WT1    = (size_t)9 * 2 * 4 * 64 * 8 * 2;   // 73.7 KB
    const size_t SZ_WT2    = (size_t)9 * 2 * 4 * 32 * 8 * 2;   // 36.9 KB
    const size_t SZ_WT3    = (size_t)25 * 1 * 4 * 16 * 8 * 2;  // 25.6 KB
    const size_t SZ_BUF    = (size_t)BB * HW * CC * 2;         // 33.5 MB

    float*  flow_up = (float*)ws;                         ws += SZ_FLOWUP;
    ushort* Ct      = (ushort*)ws;                        ws += SZ_CT;
    ushort* Wt1     = (ushort*)ws;                        ws += SZ_WT1;
    ushort* Wt2     = (ushort*)ws;                        ws += SZ_WT2;
    ushort* Wt3     = (ushort*)ws;                        ws += SZ_WT3;
    ushort* f2wg8   = (ushort*)ws;                        ws += SZ_BUF;   // bufB
    ushort* bufA    = (ushort*)ws;                        // f2cl -> h1/h2
    ushort* f2cl    = bufA;
    ushort* h1      = bufA;
    ushort* h2      = (ushort*)((char*)bufA + (size_t)BB * HW * 64 * 2);

    k_prep_w2<49, 64, 64, 64, 3><<<dim3((9 * 2 * 4 * 64 * 8 + 255) / 256), dim3(256), 0, stream>>>(w1, Wt1);
    k_prep_w2<64, 64, 32, 32, 3><<<dim3((9 * 2 * 4 * 32 * 8 + 255) / 256), dim3(256), 0, stream>>>(w2, Wt2);
    k_prep_w2<32, 32, 2, 16, 5><<<dim3((25 * 1 * 4 * 16 * 8 + 255) / 256), dim3(256), 0, stream>>>(w3, Wt3);

    k_flow_up<<<dim3(HH, 2, BB), dim3(WW), 0, stream>>>(flow, flow_up);
    k_prep_cl<<<dim3(2048), dim3(256), 0, stream>>>(f2, f2cl);
    k_warp2  <<<dim3(8192), dim3(256), 0, stream>>>(f2cl, flow_up, f2wg8);
    k_corr_mfma<<<dim3(1024), dim3(512), 0, stream>>>(f1, f2wg8, Ct);   // f2cl dead after this

    k_conv_lds<64, 64, 4, 2, 64, 3, 1, true,  false>
        <<<dim3(HH / 2, BB), dim3(512), 0, stream>>>(Ct, Wt1, b1, h1, nullptr, nullptr);
    k_conv_lds<64, 32, 2, 2, 32, 3, 1, true,  false>
        <<<dim3(HH / 2, BB), dim3(512), 0, stream>>>(h1, Wt2, b2, h2, nullptr, nullptr);
    k_conv_lds<32, 16, 1, 2, 2,  5, 2, false, true >
        <<<dim3(HH / 2, BB), dim3(512), 0, stream>>>(h2, Wt3, b3, nullptr, flow_up, out);
}